// Round 5
// baseline (279.426 us; speedup 1.0000x reference)
//
#include <hip/hip_runtime.h>
#include <hip/hip_bf16.h>

#define DEVI __device__ __forceinline__

typedef __attribute__((ext_vector_type(8))) short bf16x8;
typedef __attribute__((ext_vector_type(4))) float f32x4;
typedef __attribute__((ext_vector_type(4))) float fl4;
typedef __attribute__((ext_vector_type(4))) unsigned int u32x4;

DEVI unsigned short f2bf(float f) {
  union { float f; unsigned u; } x; x.f = f;
  unsigned r = (x.u + 0x7fffu + ((x.u >> 16) & 1u)) >> 16;
  return (unsigned short)r;
}

DEVI unsigned cvtpk(float lo, float hi) {
  unsigned r;
  asm("v_cvt_pk_bf16_f32 %0, %1, %2" : "=v"(r) : "v"(lo), "v"(hi));
  return r;
}

DEVI float fadd3(float a, float b, float c) {
  return __fadd_rn(__fadd_rn(a, b), c);
}

// ---------------------------------------------------------------- prep
// Weights -> bf16, FLAT (layout is already [o][k] row-major = what the GEMM's
// direct-from-global B reads want). BN folded into (A,B): relu(dot*A + B).
__global__ __launch_bounds__(256) void prep_kernel(
    const float* __restrict__ Ws, const float* __restrict__ Wt0,
    const float* __restrict__ Wt123,
    const float* __restrict__ bWs, const float* __restrict__ gs,
    const float* __restrict__ bes, const float* __restrict__ mus,
    const float* __restrict__ vs,
    const float* __restrict__ bWt, const float* __restrict__ gt,
    const float* __restrict__ bet, const float* __restrict__ mut,
    const float* __restrict__ vt,
    unsigned short* __restrict__ wlin, float* __restrict__ bnA,
    float* __restrict__ bnB) {
  const unsigned id = blockIdx.x * 256u + threadIdx.x;
  const unsigned WN = 2883584u;
  if (id < WN) {
    float f;
    if (id < 1048576u) f = Ws[id];
    else if (id < 2097152u) f = Wt0[id - 1048576u];
    else f = Wt123[id - 2097152u];
    wlin[id] = f2bf(f);
  } else if (id < WN + 8192u) {
    unsigned r = id - WN;
    unsigned c = r >> 10, o = r & 1023u;
    float g, bW, mu, v, be;
    if (c < 4u) { g = gs[r]; bW = bWs[r]; mu = mus[r]; v = vs[r]; be = bes[r]; }
    else {
      unsigned r2 = (c - 4u) * 1024u + o;
      g = gt[r2]; bW = bWt[r2]; mu = mut[r2]; v = vt[r2]; be = bet[r2];
    }
    float A = g / sqrtf(v + 1e-5f);
    float B = (bW - mu) * A + be;
    bnA[r] = A; bnB[r] = B;
  }
}

// ---------------------------------------------------------------- FPS
__global__ __launch_bounds__(64) void fps_kernel(const float* __restrict__ xt3,
                                                 float* __restrict__ newxyz) {
  const int b = blockIdx.x;
  const int t = threadIdx.x;
  const float* P = xt3 + (size_t)b * 256 * 3;
  float px[4], py[4], pz[4], d2[4];
#pragma unroll
  for (int j = 0; j < 4; ++j) {
    int p = t + 64 * j;
    px[j] = P[p * 3 + 0]; py[j] = P[p * 3 + 1]; pz[j] = P[p * 3 + 2];
    d2[j] = 1e10f;
  }
  float* NX = newxyz + (size_t)b * 64 * 3;
  float cx = __shfl(px[0], 0), cy = __shfl(py[0], 0), cz = __shfl(pz[0], 0);
  if (t == 0) { NX[0] = cx; NX[1] = cy; NX[2] = cz; }
  for (int i = 1; i < 64; ++i) {
    float bv = -1.0f; int bi = 0;
#pragma unroll
    for (int j = 0; j < 4; ++j) {
      float dx = __fsub_rn(px[j], cx), dy = __fsub_rn(py[j], cy),
            dz = __fsub_rn(pz[j], cz);
      float d = fadd3(__fmul_rn(dx, dx), __fmul_rn(dy, dy), __fmul_rn(dz, dz));
      d2[j] = fminf(d2[j], d);
      int p = t + 64 * j;
      if (j == 0) { bv = d2[0]; bi = t; }
      else if (d2[j] > bv) { bv = d2[j]; bi = p; }
    }
#pragma unroll
    for (int off = 32; off >= 1; off >>= 1) {
      float ov = __shfl_xor(bv, off);
      int oi = __shfl_xor(bi, off);
      if (ov > bv || (ov == bv && oi < bi)) { bv = ov; bi = oi; }
    }
    int s = bi;
    int owner = s & 63, slot = s >> 6;
    float sx = slot == 0 ? px[0] : slot == 1 ? px[1] : slot == 2 ? px[2] : px[3];
    float sy = slot == 0 ? py[0] : slot == 1 ? py[1] : slot == 2 ? py[2] : py[3];
    float sz = slot == 0 ? pz[0] : slot == 1 ? pz[1] : slot == 2 ? pz[2] : pz[3];
    cx = __shfl(sx, owner); cy = __shfl(sy, owner); cz = __shfl(sz, owner);
    if (t == 0) { NX[i * 3 + 0] = cx; NX[i * 3 + 1] = cy; NX[i * 3 + 2] = cz; }
  }
}

// ---------------------------------------------------------------- KNN
template <int NJ>
DEVI void knn_run(int lane, const float* __restrict__ X, float qx, float qy,
                  float qz, float qq, int* __restrict__ out) {
  float d2[NJ];
#pragma unroll
  for (int j = 0; j < NJ; ++j) {
    int pi = lane + 64 * j;
    float x = X[pi * 3 + 0], y = X[pi * 3 + 1], z = X[pi * 3 + 2];
    float xx = fadd3(__fmul_rn(x, x), __fmul_rn(y, y), __fmul_rn(z, z));
    float dot = fadd3(__fmul_rn(qx, x), __fmul_rn(qy, y), __fmul_rn(qz, z));
    d2[j] = __fadd_rn(__fsub_rn(qq, __fmul_rn(2.0f, dot)), xx);
  }
  for (int kk = 0; kk < 12; ++kk) {
    float bv = d2[0]; int bi = lane;
#pragma unroll
    for (int j = 1; j < NJ; ++j) {
      if (d2[j] < bv) { bv = d2[j]; bi = lane + 64 * j; }
    }
#pragma unroll
    for (int off = 1; off <= 32; off <<= 1) {
      float ov = __shfl_xor(bv, off);
      int oi = __shfl_xor(bi, off);
      if (ov < bv || (ov == bv && oi < bi)) { bv = ov; bi = oi; }
    }
    if (lane == 0) out[kk] = bi;
#pragma unroll
    for (int j = 0; j < NJ; ++j)
      if (bi == lane + 64 * j) d2[j] = 3.4e38f;
  }
}

struct KnnP { const float* xyz[8]; };

__global__ __launch_bounds__(256) void knn_kernel(KnnP p,
                                                  const float* __restrict__ newxyz,
                                                  int* __restrict__ idxbuf) {
  const int q = blockIdx.x * 4 + (threadIdx.x >> 6);
  const int lane = threadIdx.x & 63;
  const int c = q >> 10, b = (q >> 6) & 15, g = q & 63;
  const int n = 2048 >> (c & 3);
  const float* X = p.xyz[c] + (size_t)b * n * 3;
  const float* qp = newxyz + ((size_t)b * 64 + g) * 3;
  float qx = qp[0], qy = qp[1], qz = qp[2];
  float qq = fadd3(__fmul_rn(qx, qx), __fmul_rn(qy, qy), __fmul_rn(qz, qz));
  int* out = idxbuf + (size_t)q * 12;
  switch (c & 3) {
    case 0: knn_run<32>(lane, X, qx, qy, qz, qq, out); break;
    case 1: knn_run<16>(lane, X, qx, qy, qz, qq, out); break;
    case 2: knn_run<8>(lane, X, qx, qy, qz, qq, out); break;
    default: knn_run<4>(lane, X, qx, qy, qz, qq, out); break;
  }
}

// ---------------------------------------------------------------- fused GEMM
// 256x256 tile, BK=64, 8 waves (2Mx4N, per-wave 128x64).
// A: gathered f32 feats -> reg-staged -> cvt_pk bf16 -> XOR-swizzled ds_write
//    (dbuf 2x32KB, 1-deep prefetch, one barrier per K-tile). Gather fused.
// B: bf16 weights read DIRECTLY from global (L1/L2-resident) into registers --
//    no LDS at all. LDS bytes/K-tile: 256KB -> 160KB (the measured 30% MfmaUtil
//    == 614/2048 LDS-bound ceiling rises to ~49%).
struct GemmFP {
  const float* feat[8];
  unsigned woffE[8];
  unsigned outoff[8];
  int K[8];
  int n[8];
};

__global__ __launch_bounds__(512, 2) void gemm_fused_kernel(
    const unsigned short* __restrict__ wlin, const float* __restrict__ bnA,
    const float* __restrict__ bnB, const int* __restrict__ idxbuf,
    float* __restrict__ out, GemmFP p) {
  __shared__ __align__(16) char smem[65536];  // 2 x 32KB A double-buffer
  const int bid = blockIdx.x;
  const int xcd = bid & 7;
  const int tb = bid >> 3;
  const int z = tb >> 5;
  const int rem = (xcd << 5) | (tb & 31);
  const int mtile = rem >> 2, ntile = rem & 3;
  const int K = p.K[z];
  const int NKT = K >> 6;
  const int nPts = p.n[z];
  const float* feat = p.feat[z];
  const unsigned short* Bg = wlin + p.woffE[z];

  const int tid = threadIdx.x;
  const int lane = tid & 63, wid = tid >> 6;
  const int wr = wid >> 2, wc = wid & 3;

  // ---- A staging: thread covers row arow, 128B half `ahalf` of its 256B k-slice
  const int arow = tid >> 1;      // 0..255
  const int ahalf = tid & 1;
  int gl = arow >> 4;
  int kslot = arow & 15;
  int ke = (kslot < 12) ? kslot : 0;
  int group = mtile * 16 + gl;
  int pidx = idxbuf[z * 12288 + group * 12 + ke];
  int bb = group >> 6;
  const float* asrc = feat + ((size_t)bb * nPts + pidx) * K + ahalf * 32;
  const unsigned awb = (unsigned)(arow * 128 + ahalf * 64);
  const unsigned aswz = (unsigned)((arow & 7) << 4);

  // ---- frag read addressing (swizzled, matches write XOR)
  const int hi16 = (lane >> 4) * 16;
  const int swz = (lane & 7) << 4;
  const int rowA = wr * 16384 + (lane & 15) * 128;

  // ---- B column element-offsets (col * K), 4 cols per wave-thread
  const int koff = (lane >> 4) * 8;
  unsigned colK[4];
#pragma unroll
  for (int n = 0; n < 4; ++n)
    colK[n] = (unsigned)((ntile * 256 + wc * 64 + n * 16 + (lane & 15)) * K);

  f32x4 acc[8][4];
#pragma unroll
  for (int m = 0; m < 8; ++m)
#pragma unroll
    for (int n = 0; n < 4; ++n) acc[m][n] = (f32x4){0.f, 0.f, 0.f, 0.f};

  fl4 aH[8];
  auto issueA = [&](int kt2) {
    const fl4* s = (const fl4*)(asrc + kt2 * 64);
#pragma unroll
    for (int i = 0; i < 8; ++i) aH[i] = s[i];
  };
  auto writeA = [&](int buf) {
    char* dst = smem + buf * 32768;
#pragma unroll
    for (int g = 0; g < 4; ++g) {
      u32x4 w;
      w[0] = cvtpk(aH[2 * g][0], aH[2 * g][1]);
      w[1] = cvtpk(aH[2 * g][2], aH[2 * g][3]);
      w[2] = cvtpk(aH[2 * g + 1][0], aH[2 * g + 1][1]);
      w[3] = cvtpk(aH[2 * g + 1][2], aH[2 * g + 1][3]);
      *(u32x4*)(dst + ((awb + g * 16u) ^ aswz)) = w;
    }
  };

  // prologue: stage A(0), prefetch A(1)
  issueA(0);
  writeA(0);
  if (NKT > 1) issueA(1);
  __syncthreads();

  for (int kt = 0; kt < NKT; ++kt) {
    // B(kt) direct from global -> regs (L1/L2)
    bf16x8 bv[2][4];
#pragma unroll
    for (int ks = 0; ks < 2; ++ks)
#pragma unroll
      for (int n = 0; n < 4; ++n)
        bv[ks][n] = *(const bf16x8*)(Bg + colK[n] + kt * 64 + ks * 32 + koff);

    // stage A(kt+1) into the other buffer (safe: all waves done reading it)
    if (kt + 1 < NKT) writeA((kt + 1) & 1);

    const char* As = smem + (kt & 1) * 32768;
#pragma unroll
    for (int ks = 0; ks < 2; ++ks) {
      bf16x8 af[4];
#pragma unroll
      for (int j = 0; j < 4; ++j)
        af[j] = *reinterpret_cast<const bf16x8*>(
            As + ((rowA + j * 2048 + ks * 64 + hi16) ^ swz));
#pragma unroll
      for (int j = 0; j < 4; ++j)
#pragma unroll
        for (int n = 0; n < 4; ++n)
          acc[j][n] = __builtin_amdgcn_mfma_f32_16x16x32_bf16(
              af[j], bv[ks][n], acc[j][n], 0, 0, 0);
#pragma unroll
      for (int j = 0; j < 4; ++j)
        af[j] = *reinterpret_cast<const bf16x8*>(
            As + ((rowA + (4 + j) * 2048 + ks * 64 + hi16) ^ swz));
#pragma unroll
      for (int j = 0; j < 4; ++j)
#pragma unroll
        for (int n = 0; n < 4; ++n)
          acc[4 + j][n] = __builtin_amdgcn_mfma_f32_16x16x32_bf16(
              af[j], bv[ks][n], acc[4 + j][n], 0, 0, 0);
    }

    // prefetch A(kt+2) f32 into regs (latency hidden across barrier + next iter)
    if (kt + 2 < NKT) issueA(kt + 2);
    __syncthreads();
  }

  const float* bA = bnA + (unsigned)z * 1024u;
  const float* bB = bnB + (unsigned)z * 1024u;
  float* O = out + (size_t)p.outoff[z];
#pragma unroll
  for (int n = 0; n < 4; ++n) {
    int o = ntile * 256 + wc * 64 + n * 16 + (lane & 15);
    float sA = bA[o], sB = bB[o];
#pragma unroll
    for (int m = 0; m < 8; ++m) {
      float v = fmaxf(fmaxf(acc[m][n][0], acc[m][n][1]),
                      fmaxf(acc[m][n][2], acc[m][n][3]));
      v = fmaxf(v, __shfl_xor(v, 16));
      v = fmaxf(v, __shfl_xor(v, 32));
      if (lane < 16) {
        int grp = mtile * 16 + wr * 8 + m;
        float val = fmaf(v, sA, sB);
        O[(size_t)grp * 1024 + o] = fmaxf(val, 0.f);
      }
    }
  }
}

// ---------------------------------------------------------------- host
extern "C" void kernel_launch(void* const* d_in, const int* in_sizes, int n_in,
                              void* d_out, int out_size, void* d_ws,
                              size_t ws_size, hipStream_t stream) {
  (void)in_sizes; (void)n_in; (void)out_size; (void)ws_size;
  const float *fs[4], *xs[4], *ft[4], *xt[4];
  for (int i = 0; i < 4; ++i) {
    fs[i] = (const float*)d_in[4 * i + 0];
    xs[i] = (const float*)d_in[4 * i + 1];
    ft[i] = (const float*)d_in[4 * i + 2];
    xt[i] = (const float*)d_in[4 * i + 3];
  }
  const float* Ws = (const float*)d_in[16];
  const float* bWs = (const float*)d_in[17];
  const float* gs = (const float*)d_in[18];
  const float* bes = (const float*)d_in[19];
  const float* mus = (const float*)d_in[20];
  const float* vs = (const float*)d_in[21];
  const float* Wt0 = (const float*)d_in[22];
  const float* Wt123 = (const float*)d_in[23];
  const float* bWt = (const float*)d_in[24];
  const float* gt = (const float*)d_in[25];
  const float* bet = (const float*)d_in[26];
  const float* mut = (const float*)d_in[27];
  const float* vt = (const float*)d_in[28];

  char* ws = (char*)d_ws;
  float* newxyz = (float*)(ws + 0);
  int* idxbuf = (int*)(ws + 16384);
  float* bnA = (float*)(ws + 409600);
  float* bnB = (float*)(ws + 442368);
  unsigned short* wlin = (unsigned short*)(ws + 475136);  // 5767168 B

  static const int NSarr[4] = {2048, 1024, 512, 256};

  prep_kernel<<<11296, 256, 0, stream>>>(Ws, Wt0, Wt123, bWs, gs, bes, mus, vs,
                                         bWt, gt, bet, mut, vt, wlin, bnA, bnB);
  fps_kernel<<<16, 64, 0, stream>>>(xt[3], newxyz);

  KnnP kp;
  for (int i = 0; i < 4; ++i) {
    kp.xyz[i] = xs[i];
    kp.xyz[4 + i] = xt[i];
  }
  knn_kernel<<<2048, 256, 0, stream>>>(kp, newxyz, idxbuf);

  GemmFP gp;
  for (int c = 0; c < 8; ++c) {
    int scale = c & 3;
    gp.feat[c] = (c < 4) ? fs[scale] : ft[scale];
    gp.n[c] = NSarr[scale];
    gp.K[c] = (c == 4) ? 1024 : 256;
    gp.outoff[c] = (unsigned)c * 1048576u;
    gp.woffE[c] = (c < 4)   ? (unsigned)c * 262144u
                 : (c == 4) ? 1048576u
                            : 2097152u + (unsigned)(c - 5) * 262144u;
  }
  gemm_fused_kernel<<<2048, 512, 0, stream>>>(wlin, bnA, bnB, idxbuf,
                                              (float*)d_out, gp);
}

// Round 6
// 272.874 us; speedup vs baseline: 1.0240x; 1.0240x over previous
//
#include <hip/hip_runtime.h>
#include <hip/hip_bf16.h>

#define DEVI __device__ __forceinline__

typedef __attribute__((ext_vector_type(8))) short bf16x8;
typedef __attribute__((ext_vector_type(4))) float f32x4;
typedef __attribute__((ext_vector_type(4))) float fl4;
typedef __attribute__((ext_vector_type(4))) unsigned int u32x4;

DEVI unsigned short f2bf(float f) {
  union { float f; unsigned u; } x; x.f = f;
  unsigned r = (x.u + 0x7fffu + ((x.u >> 16) & 1u)) >> 16;
  return (unsigned short)r;
}

DEVI unsigned cvtpk(float lo, float hi) {
  unsigned r;
  asm("v_cvt_pk_bf16_f32 %0, %1, %2" : "=v"(r) : "v"(lo), "v"(hi));
  return r;
}

DEVI float fadd3(float a, float b, float c) {
  return __fadd_rn(__fadd_rn(a, b), c);
}

// ---------------------------------------------------------------- prep
// Weights -> bf16, PRE-SWIZZLED per-(combo, ntile, kt) 32KB blocks:
// elem (o',kl) at byte ((o'*128 + kl*2) ^ ((o'&7)<<4)). BN folded to (A,B).
__global__ __launch_bounds__(256) void prep_kernel(
    const float* __restrict__ Ws, const float* __restrict__ Wt0,
    const float* __restrict__ Wt123,
    const float* __restrict__ bWs, const float* __restrict__ gs,
    const float* __restrict__ bes, const float* __restrict__ mus,
    const float* __restrict__ vs,
    const float* __restrict__ bWt, const float* __restrict__ gt,
    const float* __restrict__ bet, const float* __restrict__ mut,
    const float* __restrict__ vt,
    char* __restrict__ wbf, float* __restrict__ bnA,
    float* __restrict__ bnB) {
  const unsigned id = blockIdx.x * 256u + threadIdx.x;
  const unsigned WN = 2883584u;
  if (id < WN) {
    float val; unsigned c, o, k, woffE;
    if (id < 1048576u) {
      c = id >> 18; unsigned rem = id & 262143u;
      o = rem >> 8; k = rem & 255u; val = Ws[id]; woffE = c << 18;
    } else if (id < 2097152u) {
      c = 4u; unsigned rem = id - 1048576u;
      o = rem >> 10; k = rem & 1023u; val = Wt0[rem]; woffE = 1048576u;
    } else {
      unsigned rem = id - 2097152u; unsigned cc = rem >> 18;
      c = 5u + cc; unsigned r2 = rem & 262143u;
      o = r2 >> 8; k = r2 & 255u; val = Wt123[rem];
      woffE = 2097152u + (cc << 18);
    }
    unsigned NKT = (c == 4u) ? 16u : 4u;
    unsigned ntile = o >> 8, op = o & 255u, kt = k >> 6, kl = k & 63u;
    unsigned byteoff = (woffE << 1) + ((ntile * NKT + kt) << 15) +
                       ((op * 128u + kl * 2u) ^ ((op & 7u) << 4));
    *(unsigned short*)(wbf + byteoff) = f2bf(val);
  } else if (id < WN + 8192u) {
    unsigned r = id - WN;
    unsigned c = r >> 10, o = r & 1023u;
    float g, bW, mu, v, be;
    if (c < 4u) { g = gs[r]; bW = bWs[r]; mu = mus[r]; v = vs[r]; be = bes[r]; }
    else {
      unsigned r2 = (c - 4u) * 1024u + o;
      g = gt[r2]; bW = bWt[r2]; mu = mut[r2]; v = vt[r2]; be = bet[r2];
    }
    float A = g / sqrtf(v + 1e-5f);
    float B = (bW - mu) * A + be;
    bnA[r] = A; bnB[r] = B;
  }
}

// ---------------------------------------------------------------- FPS
__global__ __launch_bounds__(64) void fps_kernel(const float* __restrict__ xt3,
                                                 float* __restrict__ newxyz) {
  const int b = blockIdx.x;
  const int t = threadIdx.x;
  const float* P = xt3 + (size_t)b * 256 * 3;
  float px[4], py[4], pz[4], d2[4];
#pragma unroll
  for (int j = 0; j < 4; ++j) {
    int p = t + 64 * j;
    px[j] = P[p * 3 + 0]; py[j] = P[p * 3 + 1]; pz[j] = P[p * 3 + 2];
    d2[j] = 1e10f;
  }
  float* NX = newxyz + (size_t)b * 64 * 3;
  float cx = __shfl(px[0], 0), cy = __shfl(py[0], 0), cz = __shfl(pz[0], 0);
  if (t == 0) { NX[0] = cx; NX[1] = cy; NX[2] = cz; }
  for (int i = 1; i < 64; ++i) {
    float bv = -1.0f; int bi = 0;
#pragma unroll
    for (int j = 0; j < 4; ++j) {
      float dx = __fsub_rn(px[j], cx), dy = __fsub_rn(py[j], cy),
            dz = __fsub_rn(pz[j], cz);
      float d = fadd3(__fmul_rn(dx, dx), __fmul_rn(dy, dy), __fmul_rn(dz, dz));
      d2[j] = fminf(d2[j], d);
      int p = t + 64 * j;
      if (j == 0) { bv = d2[0]; bi = t; }
      else if (d2[j] > bv) { bv = d2[j]; bi = p; }
    }
#pragma unroll
    for (int off = 32; off >= 1; off >>= 1) {
      float ov = __shfl_xor(bv, off);
      int oi = __shfl_xor(bi, off);
      if (ov > bv || (ov == bv && oi < bi)) { bv = ov; bi = oi; }
    }
    int s = bi;
    int owner = s & 63, slot = s >> 6;
    float sx = slot == 0 ? px[0] : slot == 1 ? px[1] : slot == 2 ? px[2] : px[3];
    float sy = slot == 0 ? py[0] : slot == 1 ? py[1] : slot == 2 ? py[2] : py[3];
    float sz = slot == 0 ? pz[0] : slot == 1 ? pz[1] : slot == 2 ? pz[2] : pz[3];
    cx = __shfl(sx, owner); cy = __shfl(sy, owner); cz = __shfl(sz, owner);
    if (t == 0) { NX[i * 3 + 0] = cx; NX[i * 3 + 1] = cy; NX[i * 3 + 2] = cz; }
  }
}

// ---------------------------------------------------------------- KNN
template <int NJ>
DEVI void knn_run(int lane, const float* __restrict__ X, float qx, float qy,
                  float qz, float qq, int* __restrict__ out) {
  float d2[NJ];
#pragma unroll
  for (int j = 0; j < NJ; ++j) {
    int pi = lane + 64 * j;
    float x = X[pi * 3 + 0], y = X[pi * 3 + 1], z = X[pi * 3 + 2];
    float xx = fadd3(__fmul_rn(x, x), __fmul_rn(y, y), __fmul_rn(z, z));
    float dot = fadd3(__fmul_rn(qx, x), __fmul_rn(qy, y), __fmul_rn(qz, z));
    d2[j] = __fadd_rn(__fsub_rn(qq, __fmul_rn(2.0f, dot)), xx);
  }
  for (int kk = 0; kk < 12; ++kk) {
    float bv = d2[0]; int bi = lane;
#pragma unroll
    for (int j = 1; j < NJ; ++j) {
      if (d2[j] < bv) { bv = d2[j]; bi = lane + 64 * j; }
    }
#pragma unroll
    for (int off = 1; off <= 32; off <<= 1) {
      float ov = __shfl_xor(bv, off);
      int oi = __shfl_xor(bi, off);
      if (ov < bv || (ov == bv && oi < bi)) { bv = ov; bi = oi; }
    }
    if (lane == 0) out[kk] = bi;
#pragma unroll
    for (int j = 0; j < NJ; ++j)
      if (bi == lane + 64 * j) d2[j] = 3.4e38f;
  }
}

struct KnnP { const float* xyz[8]; };

__global__ __launch_bounds__(256) void knn_kernel(KnnP p,
                                                  const float* __restrict__ newxyz,
                                                  int* __restrict__ idxbuf) {
  const int q = blockIdx.x * 4 + (threadIdx.x >> 6);
  const int lane = threadIdx.x & 63;
  const int c = q >> 10, b = (q >> 6) & 15, g = q & 63;
  const int n = 2048 >> (c & 3);
  const float* X = p.xyz[c] + (size_t)b * n * 3;
  const float* qp = newxyz + ((size_t)b * 64 + g) * 3;
  float qx = qp[0], qy = qp[1], qz = qp[2];
  float qq = fadd3(__fmul_rn(qx, qx), __fmul_rn(qy, qy), __fmul_rn(qz, qz));
  int* out = idxbuf + (size_t)q * 12;
  switch (c & 3) {
    case 0: knn_run<32>(lane, X, qx, qy, qz, qq, out); break;
    case 1: knn_run<16>(lane, X, qx, qy, qz, qq, out); break;
    case 2: knn_run<8>(lane, X, qx, qy, qz, qq, out); break;
    default: knn_run<4>(lane, X, qx, qy, qz, qq, out); break;
  }
}

// ---------------------------------------------------------------- persistent fused GEMM
// 256 blocks (1/CU), 512 thr, 8 waves (2Mx4N, per-wave 128x64). Each block owns
// 8 tiles (one per combo, same (mtile,ntile)) -> 44 continuous K-steps.
// Depth-1 pipeline: at step g issue B global_load_lds(g+1) + A f32 reg-gather
// (g+1) into the idle buffers; MFMA(g); cvt_pk + swizzled ds_write A(g+1);
// one __syncthreads per step. Gather fused; prologue paid once per CU.
struct GemmPP {
  const float* feat[8];
  int n[8];
  int K[8];
  unsigned woffB[8];   // byte offsets into wbf
};

#define GLOAD_LDS16(gsrc, ldsdst)                                              \
  __builtin_amdgcn_global_load_lds(                                            \
      (const __attribute__((address_space(1))) void*)(gsrc),                   \
      (__attribute__((address_space(3))) void*)(ldsdst), 16, 0, 0)

__global__ __launch_bounds__(512, 2) void gemm_pers_kernel(
    const char* __restrict__ wbf, const float* __restrict__ bnA,
    const float* __restrict__ bnB, const int* __restrict__ idxbuf,
    float* __restrict__ out, GemmPP p) {
  extern __shared__ char smem[];  // [A0 32K][A1 32K][B0 32K][B1 32K]
  const int bid = blockIdx.x;
  const int xcd = bid & 7, slot = bid >> 3;
  const int rem = (xcd << 5) | slot;
  const int mtile = rem >> 2, ntile = rem & 3;
  const int tid = threadIdx.x;
  const int lane = tid & 63, wid = tid >> 6;
  const int wr = wid >> 2, wc = wid & 3;

  // A staging: thread covers (row=tid>>1, 128B half=tid&1) of the 256-row tile
  const int arow = tid >> 1, ahalf = tid & 1;
  const int gl = arow >> 4, kslot = arow & 15;
  const int ke = (kslot < 12) ? kslot : 0;
  const int group = mtile * 16 + gl;
  const int bb = group >> 6;
  const unsigned awb = (unsigned)(arow * 128 + ahalf * 64);
  const unsigned aswz = (unsigned)((arow & 7) << 4);

  // fragment addressing (XOR swizzle matches writes)
  const int hi16 = (lane >> 4) * 16;
  const int swz = (lane & 7) << 4;
  const int rowA = wr * 16384 + (lane & 15) * 128;
  const int colB = wc * 8192 + (lane & 15) * 128;

  f32x4 acc[8][4];
#pragma unroll
  for (int m = 0; m < 8; ++m)
#pragma unroll
    for (int n = 0; n < 4; ++n) acc[m][n] = (f32x4){0.f, 0.f, 0.f, 0.f};

  fl4 aH[8];
  auto issueA = [&](const float* src) {
    const fl4* s = (const fl4*)src;
#pragma unroll
    for (int i = 0; i < 8; ++i) aH[i] = s[i];
  };
  auto writeA = [&](int par) {
    char* dst = smem + par * 32768;
#pragma unroll
    for (int g = 0; g < 4; ++g) {
      u32x4 w;
      w[0] = cvtpk(aH[2 * g][0], aH[2 * g][1]);
      w[1] = cvtpk(aH[2 * g][2], aH[2 * g][3]);
      w[2] = cvtpk(aH[2 * g + 1][0], aH[2 * g + 1][1]);
      w[3] = cvtpk(aH[2 * g + 1][2], aH[2 * g + 1][3]);
      *(u32x4*)(dst + ((awb + g * 16u) ^ aswz)) = w;
    }
  };
  auto issueB = [&](const char* src, int par) {
    char* dst = smem + 65536 + par * 32768;
#pragma unroll
    for (int it = 0; it < 4; ++it)
      GLOAD_LDS16(src + (it * 512 + tid) * 16, dst + (it * 512 + wid * 64) * 16);
  };

  // tile 0 bases
  const float* asrcC;
  {
    int pidx = idxbuf[group * 12 + ke];
    asrcC = p.feat[0] + ((size_t)bb * p.n[0] + pidx) * p.K[0] + ahalf * 32;
  }
  const char* BgC = wbf + p.woffB[0] + (size_t)ntile * (p.K[0] >> 6) * 32768;

  // prologue: stage step (z=0, kt=0) into parity 0
  issueB(BgC, 0);
  issueA(asrcC);
  writeA(0);
  __syncthreads();

  int parity = 0;
  for (int zi = 0; zi < 8; ++zi) {
    const int nkt = p.K[zi] >> 6;
    // next tile bases (computed early: nkt steps of slack)
    const float* asrcN = nullptr;
    const char* BgN = nullptr;
    if (zi < 7) {
      int pidxN = idxbuf[(zi + 1) * 12288 + group * 12 + ke];
      asrcN = p.feat[zi + 1] +
              ((size_t)bb * p.n[zi + 1] + pidxN) * p.K[zi + 1] + ahalf * 32;
      BgN = wbf + p.woffB[zi + 1] + (size_t)ntile * (p.K[zi + 1] >> 6) * 32768;
    }
    for (int kt = 0; kt < nkt; ++kt) {
      const bool lastK = (kt == nkt - 1);
      const bool lastAll = lastK && (zi == 7);
      const int q = parity ^ 1;
      if (!lastAll) {
        const char* bN = lastK ? BgN : (BgC + (size_t)(kt + 1) * 32768);
        const float* aN = lastK ? asrcN : (asrcC + (kt + 1) * 64);
        issueB(bN, q);
        issueA(aN);
      }
      const char* As = smem + parity * 32768;
      const char* Bs = smem + 65536 + parity * 32768;
      bf16x8 bv[2][4];
#pragma unroll
      for (int ks = 0; ks < 2; ++ks)
#pragma unroll
        for (int n = 0; n < 4; ++n)
          bv[ks][n] = *reinterpret_cast<const bf16x8*>(
              Bs + ((colB + n * 2048 + ks * 64 + hi16) ^ swz));
#pragma unroll
      for (int ks = 0; ks < 2; ++ks) {
        bf16x8 af[4];
#pragma unroll
        for (int j = 0; j < 4; ++j)
          af[j] = *reinterpret_cast<const bf16x8*>(
              As + ((rowA + j * 2048 + ks * 64 + hi16) ^ swz));
#pragma unroll
        for (int j = 0; j < 4; ++j)
#pragma unroll
          for (int n = 0; n < 4; ++n)
            acc[j][n] = __builtin_amdgcn_mfma_f32_16x16x32_bf16(
                af[j], bv[ks][n], acc[j][n], 0, 0, 0);
#pragma unroll
        for (int j = 0; j < 4; ++j)
          af[j] = *reinterpret_cast<const bf16x8*>(
              As + ((rowA + (4 + j) * 2048 + ks * 64 + hi16) ^ swz));
#pragma unroll
        for (int j = 0; j < 4; ++j)
#pragma unroll
          for (int n = 0; n < 4; ++n)
            acc[4 + j][n] = __builtin_amdgcn_mfma_f32_16x16x32_bf16(
                af[j], bv[ks][n], acc[4 + j][n], 0, 0, 0);
      }
      __builtin_amdgcn_sched_barrier(0);   // keep A cvt/ds_write below MFMA
      if (!lastAll) writeA(q);
      __syncthreads();
      parity ^= 1;
    }
    // ---- epilogue tile zi: max over 16 rows + BN + ReLU
    const float* bA = bnA + zi * 1024;
    const float* bB = bnB + zi * 1024;
    float* O = out + (size_t)zi * 1048576u;
#pragma unroll
    for (int n = 0; n < 4; ++n) {
      int o = ntile * 256 + wc * 64 + n * 16 + (lane & 15);
      float sA = bA[o], sB = bB[o];
#pragma unroll
      for (int m = 0; m < 8; ++m) {
        float v = fmaxf(fmaxf(acc[m][n][0], acc[m][n][1]),
                        fmaxf(acc[m][n][2], acc[m][n][3]));
        v = fmaxf(v, __shfl_xor(v, 16));
        v = fmaxf(v, __shfl_xor(v, 32));
        if (lane < 16) {
          int grp = mtile * 16 + wr * 8 + m;
          float val = fmaf(v, sA, sB);
          O[(size_t)grp * 1024 + o] = fmaxf(val, 0.f);
        }
      }
    }
#pragma unroll
    for (int m = 0; m < 8; ++m)
#pragma unroll
      for (int n = 0; n < 4; ++n) acc[m][n] = (f32x4){0.f, 0.f, 0.f, 0.f};
    asrcC = asrcN;
    BgC = BgN;
  }
}

// ---------------------------------------------------------------- host
extern "C" void kernel_launch(void* const* d_in, const int* in_sizes, int n_in,
                              void* d_out, int out_size, void* d_ws,
                              size_t ws_size, hipStream_t stream) {
  (void)in_sizes; (void)n_in; (void)out_size; (void)ws_size;
  const float *fs[4], *xs[4], *ft[4], *xt[4];
  for (int i = 0; i < 4; ++i) {
    fs[i] = (const float*)d_in[4 * i + 0];
    xs[i] = (const float*)d_in[4 * i + 1];
    ft[i] = (const float*)d_in[4 * i + 2];
    xt[i] = (const float*)d_in[4 * i + 3];
  }
  const float* Ws = (const float*)d_in[16];
  const float* bWs = (const float*)d_in[17];
  const float* gs = (const float*)d_in[18];
  const float* bes = (const float*)d_in[19];
  const float* mus = (const float*)d_in[20];
  const float* vs = (const float*)d_in[21];
  const float* Wt0 = (const float*)d_in[22];
  const float* Wt123 = (const float*)d_in[23];
  const float* bWt = (const float*)d_in[24];
  const float* gt = (const float*)d_in[25];
  const float* bet = (const float*)d_in[26];
  const float* mut = (const float*)d_in[27];
  const float* vt = (const float*)d_in[28];

  char* ws = (char*)d_ws;
  float* newxyz = (float*)(ws + 0);
  int* idxbuf = (int*)(ws + 16384);
  float* bnA = (float*)(ws + 409600);
  float* bnB = (float*)(ws + 442368);
  char* wbf = ws + 475136;   // 5767168 B, pre-swizzled B blocks

  static const int NSarr[4] = {2048, 1024, 512, 256};

  prep_kernel<<<11296, 256, 0, stream>>>(Ws, Wt0, Wt123, bWs, gs, bes, mus, vs,
                                         bWt, gt, bet, mut, vt, wbf, bnA, bnB);
  fps_kernel<<<16, 64, 0, stream>>>(xt[3], newxyz);

  KnnP kp;
  for (int i = 0; i < 4; ++i) {
    kp.xyz[i] = xs[i];
    kp.xyz[4 + i] = xt[i];
  }
  knn_kernel<<<2048, 256, 0, stream>>>(kp, newxyz, idxbuf);

  GemmPP gp;
  for (int c = 0; c < 8; ++c) {
    int scale = c & 3;
    gp.feat[c] = (c < 4) ? fs[scale] : ft[scale];
    gp.n[c] = NSarr[scale];
    gp.K[c] = (c == 4) ? 1024 : 256;
    gp.woffB[c] = ((c < 4)   ? (unsigned)c * 262144u
                  : (c == 4) ? 1048576u
                             : 2097152u + (unsigned)(c - 5) * 262144u) * 2u;
  }
  (void)hipFuncSetAttribute((const void*)gemm_pers_kernel,
                            hipFuncAttributeMaxDynamicSharedMemorySize, 131072);
  gemm_pers_kernel<<<256, 512, 131072, stream>>>(wbf, bnA, bnB, idxbuf,
                                                 (float*)d_out, gp);
}

// Round 7
// 229.239 us; speedup vs baseline: 1.2189x; 1.1903x over previous
//
#include <hip/hip_runtime.h>
#include <hip/hip_bf16.h>

#define DEVI __device__ __forceinline__

typedef __attribute__((ext_vector_type(8))) short bf16x8;
typedef __attribute__((ext_vector_type(4))) float f32x4;
typedef __attribute__((ext_vector_type(8))) unsigned short us8;
typedef __attribute__((ext_vector_type(4))) float fl4;

DEVI unsigned short f2bf(float f) {
  union { float f; unsigned u; } x; x.f = f;
  unsigned r = (x.u + 0x7fffu + ((x.u >> 16) & 1u)) >> 16;
  return (unsigned short)r;
}

DEVI float fadd3(float a, float b, float c) {
  return __fadd_rn(__fadd_rn(a, b), c);
}

// ---------------------------------------------------------------- prep
// Weights -> bf16, PRE-SWIZZLED per-(combo, ntile, kt) 32KB blocks:
// elem (o',kl) at byte ((o'*128 + kl*2) ^ ((o'&7)<<4)). BN folded to (A,B).
__global__ __launch_bounds__(256) void prep_kernel(
    const float* __restrict__ Ws, const float* __restrict__ Wt0,
    const float* __restrict__ Wt123,
    const float* __restrict__ bWs, const float* __restrict__ gs,
    const float* __restrict__ bes, const float* __restrict__ mus,
    const float* __restrict__ vs,
    const float* __restrict__ bWt, const float* __restrict__ gt,
    const float* __restrict__ bet, const float* __restrict__ mut,
    const float* __restrict__ vt,
    char* __restrict__ wbf, float* __restrict__ bnA,
    float* __restrict__ bnB) {
  const unsigned id = blockIdx.x * 256u + threadIdx.x;
  const unsigned WN = 2883584u;
  if (id < WN) {
    float val; unsigned c, o, k, woffE;
    if (id < 1048576u) {
      c = id >> 18; unsigned rem = id & 262143u;
      o = rem >> 8; k = rem & 255u; val = Ws[id]; woffE = c << 18;
    } else if (id < 2097152u) {
      c = 4u; unsigned rem = id - 1048576u;
      o = rem >> 10; k = rem & 1023u; val = Wt0[rem]; woffE = 1048576u;
    } else {
      unsigned rem = id - 2097152u; unsigned cc = rem >> 18;
      c = 5u + cc; unsigned r2 = rem & 262143u;
      o = r2 >> 8; k = r2 & 255u; val = Wt123[rem];
      woffE = 2097152u + (cc << 18);
    }
    unsigned NKT = (c == 4u) ? 16u : 4u;
    unsigned ntile = o >> 8, op = o & 255u, kt = k >> 6, kl = k & 63u;
    unsigned byteoff = (woffE << 1) + ((ntile * NKT + kt) << 15) +
                       ((op * 128u + kl * 2u) ^ ((op & 7u) << 4));
    *(unsigned short*)(wbf + byteoff) = f2bf(val);
  } else if (id < WN + 8192u) {
    unsigned r = id - WN;
    unsigned c = r >> 10, o = r & 1023u;
    float g, bW, mu, v, be;
    if (c < 4u) { g = gs[r]; bW = bWs[r]; mu = mus[r]; v = vs[r]; be = bes[r]; }
    else {
      unsigned r2 = (c - 4u) * 1024u + o;
      g = gt[r2]; bW = bWt[r2]; mu = mut[r2]; v = vt[r2]; be = bet[r2];
    }
    float A = g / sqrtf(v + 1e-5f);
    float B = (bW - mu) * A + be;
    bnA[r] = A; bnB[r] = B;
  }
}

// ---------------------------------------------------------------- FPS
__global__ __launch_bounds__(64) void fps_kernel(const float* __restrict__ xt3,
                                                 float* __restrict__ newxyz) {
  const int b = blockIdx.x;
  const int t = threadIdx.x;
  const float* P = xt3 + (size_t)b * 256 * 3;
  float px[4], py[4], pz[4], d2[4];
#pragma unroll
  for (int j = 0; j < 4; ++j) {
    int p = t + 64 * j;
    px[j] = P[p * 3 + 0]; py[j] = P[p * 3 + 1]; pz[j] = P[p * 3 + 2];
    d2[j] = 1e10f;
  }
  float* NX = newxyz + (size_t)b * 64 * 3;
  float cx = __shfl(px[0], 0), cy = __shfl(py[0], 0), cz = __shfl(pz[0], 0);
  if (t == 0) { NX[0] = cx; NX[1] = cy; NX[2] = cz; }
  for (int i = 1; i < 64; ++i) {
    float bv = -1.0f; int bi = 0;
#pragma unroll
    for (int j = 0; j < 4; ++j) {
      float dx = __fsub_rn(px[j], cx), dy = __fsub_rn(py[j], cy),
            dz = __fsub_rn(pz[j], cz);
      float d = fadd3(__fmul_rn(dx, dx), __fmul_rn(dy, dy), __fmul_rn(dz, dz));
      d2[j] = fminf(d2[j], d);
      int p = t + 64 * j;
      if (j == 0) { bv = d2[0]; bi = t; }
      else if (d2[j] > bv) { bv = d2[j]; bi = p; }
    }
#pragma unroll
    for (int off = 32; off >= 1; off >>= 1) {
      float ov = __shfl_xor(bv, off);
      int oi = __shfl_xor(bi, off);
      if (ov > bv || (ov == bv && oi < bi)) { bv = ov; bi = oi; }
    }
    int s = bi;
    int owner = s & 63, slot = s >> 6;
    float sx = slot == 0 ? px[0] : slot == 1 ? px[1] : slot == 2 ? px[2] : px[3];
    float sy = slot == 0 ? py[0] : slot == 1 ? py[1] : slot == 2 ? py[2] : py[3];
    float sz = slot == 0 ? pz[0] : slot == 1 ? pz[1] : slot == 2 ? pz[2] : pz[3];
    cx = __shfl(sx, owner); cy = __shfl(sy, owner); cz = __shfl(sz, owner);
    if (t == 0) { NX[i * 3 + 0] = cx; NX[i * 3 + 1] = cy; NX[i * 3 + 2] = cz; }
  }
}

// ---------------------------------------------------------------- KNN
template <int NJ>
DEVI void knn_run(int lane, const float* __restrict__ X, float qx, float qy,
                  float qz, float qq, int* __restrict__ out) {
  float d2[NJ];
#pragma unroll
  for (int j = 0; j < NJ; ++j) {
    int pi = lane + 64 * j;
    float x = X[pi * 3 + 0], y = X[pi * 3 + 1], z = X[pi * 3 + 2];
    float xx = fadd3(__fmul_rn(x, x), __fmul_rn(y, y), __fmul_rn(z, z));
    float dot = fadd3(__fmul_rn(qx, x), __fmul_rn(qy, y), __fmul_rn(qz, z));
    d2[j] = __fadd_rn(__fsub_rn(qq, __fmul_rn(2.0f, dot)), xx);
  }
  for (int kk = 0; kk < 12; ++kk) {
    float bv = d2[0]; int bi = lane;
#pragma unroll
    for (int j = 1; j < NJ; ++j) {
      if (d2[j] < bv) { bv = d2[j]; bi = lane + 64 * j; }
    }
#pragma unroll
    for (int off = 1; off <= 32; off <<= 1) {
      float ov = __shfl_xor(bv, off);
      int oi = __shfl_xor(bi, off);
      if (ov < bv || (ov == bv && oi < bi)) { bv = ov; bi = oi; }
    }
    if (lane == 0) out[kk] = bi;
#pragma unroll
    for (int j = 0; j < NJ; ++j)
      if (bi == lane + 64 * j) d2[j] = 3.4e38f;
  }
}

struct KnnP { const float* xyz[8]; };

__global__ __launch_bounds__(256) void knn_kernel(KnnP p,
                                                  const float* __restrict__ newxyz,
                                                  int* __restrict__ idxbuf) {
  const int q = blockIdx.x * 4 + (threadIdx.x >> 6);
  const int lane = threadIdx.x & 63;
  const int c = q >> 10, b = (q >> 6) & 15, g = q & 63;
  const int n = 2048 >> (c & 3);
  const float* X = p.xyz[c] + (size_t)b * n * 3;
  const float* qp = newxyz + ((size_t)b * 64 + g) * 3;
  float qx = qp[0], qy = qp[1], qz = qp[2];
  float qq = fadd3(__fmul_rn(qx, qx), __fmul_rn(qy, qy), __fmul_rn(qz, qz));
  int* out = idxbuf + (size_t)q * 12;
  switch (c & 3) {
    case 0: knn_run<32>(lane, X, qx, qy, qz, qq, out); break;
    case 1: knn_run<16>(lane, X, qx, qy, qz, qq, out); break;
    case 2: knn_run<8>(lane, X, qx, qy, qz, qq, out); break;
    default: knn_run<4>(lane, X, qx, qy, qz, qq, out); break;
  }
}

// ---------------------------------------------------------------- gather
struct GatherP {
  const float* feat[8];
  int n[8];
  unsigned base16[9];
  unsigned goffB[8];
  int lsh[8];
  int NKT[8];
};

__global__ __launch_bounds__(256) void gather_kernel(GatherP p,
                                                     const int* __restrict__ idxbuf,
                                                     char* __restrict__ grouped) {
  unsigned id = blockIdx.x * 256u + threadIdx.x;
  if (id >= p.base16[8]) return;
  int c = 0;
#pragma unroll
  for (int j = 1; j < 8; ++j) if (id >= p.base16[j]) c = j;
  unsigned local = id - p.base16[c];
  int lsh = p.lsh[c];
  unsigned r = local >> lsh;
  unsigned k8 = local & ((1u << lsh) - 1u);
  unsigned rowp = r & 255u, mtile = r >> 8, group = r >> 4, kslot = r & 15u;
  unsigned b = group >> 6;
  int ke = (kslot < 12u) ? (int)kslot : 0;
  int pidx = idxbuf[(size_t)c * 12288 + group * 12u + ke];
  int C = (lsh == 7) ? 1024 : 256;
  const float* src = p.feat[c] + ((size_t)b * p.n[c] + pidx) * C + k8 * 8u;
  fl4 v0 = *reinterpret_cast<const fl4*>(src);
  fl4 v1 = *reinterpret_cast<const fl4*>(src + 4);
  us8 ov;
  ov[0] = f2bf(v0[0]); ov[1] = f2bf(v0[1]); ov[2] = f2bf(v0[2]); ov[3] = f2bf(v0[3]);
  ov[4] = f2bf(v1[0]); ov[5] = f2bf(v1[1]); ov[6] = f2bf(v1[2]); ov[7] = f2bf(v1[3]);
  unsigned kt = k8 >> 3, kl8 = k8 & 7u;
  unsigned byteoff = p.goffB[c] + (mtile * (unsigned)p.NKT[c] + kt) * 32768u +
                     ((rowp * 128u + kl8 * 16u) ^ ((rowp & 7u) << 4));
  *reinterpret_cast<us8*>(grouped + byteoff) = ov;
}

// ---------------------------------------------------------------- GEMM
// Persistent: 256 blocks (1/CU, 8 waves 2Mx4N). Each block owns one
// (mtile,ntile) and runs ALL 8 combos as one continuous 44-step pipeline
// (light combos first, heavy K=1024 last). Depth-2 gload_lds prefetch with
// counted vmcnt(8); R4's 4-phase MFMA body; per-combo epilogue between steps.
// Arrays in GemmPR are zi-ordered (combo order {0,1,2,3,5,6,7,4}).
struct GemmPR {
  unsigned goff[8]; unsigned woff[8]; unsigned outoff[8];
  unsigned bnoff[8]; int K[8];
};

#define GLOAD_LDS16(gsrc, ldsdst)                                              \
  __builtin_amdgcn_global_load_lds(                                            \
      (const __attribute__((address_space(1))) void*)(gsrc),                   \
      (__attribute__((address_space(3))) void*)(ldsdst), 16, 0, 0)

__global__ __launch_bounds__(512, 2) void gemm_pers_kernel(
    const unsigned short* __restrict__ grouped,
    const unsigned short* __restrict__ wbf, const float* __restrict__ bnA,
    const float* __restrict__ bnB, float* __restrict__ out, GemmPR p) {
  extern __shared__ char smem[];  // 2 x [A 32K | B 32K]
  const int bid = blockIdx.x;
  const int xcd = bid & 7, slot = bid >> 3;
  const int rem = (xcd << 5) | slot;   // 4 consecutive slots share an mtile on one XCD
  const int mtile = rem >> 2, ntile = rem & 3;
  const int tid = threadIdx.x;
  const int lane = tid & 63, wid = tid >> 6;
  const int wr = wid >> 2, wc = wid & 3;

  const int hi16 = (lane >> 4) * 16;
  const int swz = (lane & 7) << 4;
  const int rowA = wr * 16384 + (lane & 15) * 128;
  const int colB = wc * 8192 + (lane & 15) * 128;

  f32x4 acc[8][4];
#pragma unroll
  for (int m = 0; m < 8; ++m)
#pragma unroll
    for (int n = 0; n < 4; ++n) acc[m][n] = (f32x4){0.f, 0.f, 0.f, 0.f};

  auto stageA = [&](int par, const char* src) {
    char* dst = smem + par * 65536;
#pragma unroll
    for (int it = 0; it < 4; ++it)
      GLOAD_LDS16(src + (it * 512 + tid) * 16, dst + (it * 512 + wid * 64) * 16);
  };
  auto stageB = [&](int par, const char* src) {
    char* dst = smem + par * 65536 + 32768;
#pragma unroll
    for (int it = 0; it < 4; ++it)
      GLOAD_LDS16(src + (it * 512 + tid) * 16, dst + (it * 512 + wid * 64) * 16);
  };

  // tile 0 bases
  int nkt = p.K[0] >> 6;
  const char* Ac = (const char*)(grouped + p.goff[0]) + (size_t)mtile * nkt * 32768;
  const char* Bc = (const char*)(wbf + p.woff[0]) + (size_t)ntile * nkt * 32768;

  // prologue: stage steps 0,1
  stageA(0, Ac); stageB(0, Bc);
  stageA(1, Ac + 32768); stageB(1, Bc + 32768);
  asm volatile("s_waitcnt vmcnt(8)" ::: "memory");
  __builtin_amdgcn_s_barrier();

  int gs = 0;      // global step [0,44)
  int par = 0;
  for (int zi = 0; zi < 8; ++zi) {
    nkt = p.K[zi] >> 6;
    const char* An = nullptr;
    const char* Bn = nullptr;
    if (zi < 7) {
      int nktN = p.K[zi + 1] >> 6;
      An = (const char*)(grouped + p.goff[zi + 1]) + (size_t)mtile * nktN * 32768;
      Bn = (const char*)(wbf + p.woff[zi + 1]) + (size_t)ntile * nktN * 32768;
    }
    for (int kt = 0; kt < nkt; ++kt, ++gs, par ^= 1) {
      const char* As = smem + par * 65536;
      const char* Bs = As + 32768;
      const bool do_stage = (gs + 2 < 44);
      const char* sA = nullptr;
      const char* sB = nullptr;
      if (do_stage) {
        int k2 = kt + 2;
        if (k2 < nkt) { sA = Ac + (size_t)k2 * 32768; sB = Bc + (size_t)k2 * 32768; }
        else { int r2 = k2 - nkt; sA = An + (size_t)r2 * 32768; sB = Bn + (size_t)r2 * 32768; }
      }
      bf16x8 af[4], bv[4];

      // ---- P0: ks=0, m=0..3 (+ all bv ks=0)
#pragma unroll
      for (int j = 0; j < 4; ++j)
        af[j] = *reinterpret_cast<const bf16x8*>(
            As + ((rowA + j * 2048 + hi16) ^ swz));
#pragma unroll
      for (int n = 0; n < 4; ++n)
        bv[n] = *reinterpret_cast<const bf16x8*>(
            Bs + ((colB + n * 2048 + hi16) ^ swz));
      __builtin_amdgcn_s_barrier();
      asm volatile("s_waitcnt lgkmcnt(0)" ::: "memory");
      __builtin_amdgcn_sched_barrier(0);
      __builtin_amdgcn_s_setprio(1);
#pragma unroll
      for (int j = 0; j < 4; ++j)
#pragma unroll
        for (int n = 0; n < 4; ++n)
          acc[j][n] = __builtin_amdgcn_mfma_f32_16x16x32_bf16(af[j], bv[n],
                                                              acc[j][n], 0, 0, 0);
      __builtin_amdgcn_s_setprio(0);
      __builtin_amdgcn_s_barrier();

      // ---- P1: ks=0, m=4..7
#pragma unroll
      for (int j = 0; j < 4; ++j)
        af[j] = *reinterpret_cast<const bf16x8*>(
            As + ((rowA + (4 + j) * 2048 + hi16) ^ swz));
      __builtin_amdgcn_s_barrier();
      asm volatile("s_waitcnt lgkmcnt(0)" ::: "memory");
      __builtin_amdgcn_sched_barrier(0);
      __builtin_amdgcn_s_setprio(1);
#pragma unroll
      for (int j = 0; j < 4; ++j)
#pragma unroll
        for (int n = 0; n < 4; ++n)
          acc[4 + j][n] = __builtin_amdgcn_mfma_f32_16x16x32_bf16(
              af[j], bv[n], acc[4 + j][n], 0, 0, 0);
      __builtin_amdgcn_s_setprio(0);
      __builtin_amdgcn_s_barrier();

      // ---- P2: ks=1, m=0..3 (+ all bv ks=1); stageB after MFMA
#pragma unroll
      for (int j = 0; j < 4; ++j)
        af[j] = *reinterpret_cast<const bf16x8*>(
            As + ((rowA + j * 2048 + 64 + hi16) ^ swz));
#pragma unroll
      for (int n = 0; n < 4; ++n)
        bv[n] = *reinterpret_cast<const bf16x8*>(
            Bs + ((colB + n * 2048 + 64 + hi16) ^ swz));
      __builtin_amdgcn_s_barrier();
      asm volatile("s_waitcnt lgkmcnt(0)" ::: "memory");
      __builtin_amdgcn_sched_barrier(0);
      __builtin_amdgcn_s_setprio(1);
#pragma unroll
      for (int j = 0; j < 4; ++j)
#pragma unroll
        for (int n = 0; n < 4; ++n)
          acc[j][n] = __builtin_amdgcn_mfma_f32_16x16x32_bf16(af[j], bv[n],
                                                              acc[j][n], 0, 0, 0);
      __builtin_amdgcn_s_setprio(0);
      if (do_stage) stageB(par, sB);
      __builtin_amdgcn_s_barrier();

      // ---- P3: ks=1, m=4..7; stageA after MFMA; counted vmcnt
#pragma unroll
      for (int j = 0; j < 4; ++j)
        af[j] = *reinterpret_cast<const bf16x8*>(
            As + ((rowA + (4 + j) * 2048 + 64 + hi16) ^ swz));
      __builtin_amdgcn_s_barrier();
      asm volatile("s_waitcnt lgkmcnt(0)" ::: "memory");
      __builtin_amdgcn_sched_barrier(0);
      __builtin_amdgcn_s_setprio(1);
#pragma unroll
      for (int j = 0; j < 4; ++j)
#pragma unroll
        for (int n = 0; n < 4; ++n)
          acc[4 + j][n] = __builtin_amdgcn_mfma_f32_16x16x32_bf16(
              af[j], bv[n], acc[4 + j][n], 0, 0, 0);
      __builtin_amdgcn_s_setprio(0);

      if (do_stage) stageA(par, sA);
      if (gs + 1 < 44) {
        if (do_stage)
          asm volatile("s_waitcnt vmcnt(8)" ::: "memory");
        else
          asm volatile("s_waitcnt vmcnt(0)" ::: "memory");
      }
      __builtin_amdgcn_sched_barrier(0);
      __builtin_amdgcn_s_barrier();
    }

    // ---- epilogue tile zi (register-only + global stores; pipeline continues)
    const float* bA = bnA + p.bnoff[zi];
    const float* bB = bnB + p.bnoff[zi];
    float* O = out + (size_t)p.outoff[zi];
#pragma unroll
    for (int n = 0; n < 4; ++n) {
      int o = ntile * 256 + wc * 64 + n * 16 + (lane & 15);
      float sA = bA[o], sB = bB[o];
#pragma unroll
      for (int m = 0; m < 8; ++m) {
        float v = fmaxf(fmaxf(acc[m][n][0], acc[m][n][1]),
                        fmaxf(acc[m][n][2], acc[m][n][3]));
        v = fmaxf(v, __shfl_xor(v, 16));
        v = fmaxf(v, __shfl_xor(v, 32));
        if (lane < 16) {
          int grp = mtile * 16 + wr * 8 + m;
          float val = fmaf(v, sA, sB);
          O[(size_t)grp * 1024 + o] = fmaxf(val, 0.f);
        }
      }
    }
#pragma unroll
    for (int m = 0; m < 8; ++m)
#pragma unroll
      for (int n = 0; n < 4; ++n) acc[m][n] = (f32x4){0.f, 0.f, 0.f, 0.f};
    Ac = An;
    Bc = Bn;
  }
}

// Fallback (single-buffer, 64KB dynamic) in case 128KB attr fails.
__global__ __launch_bounds__(512, 2) void gemm256_fb_kernel(
    const unsigned short* __restrict__ grouped,
    const unsigned short* __restrict__ wbf, const float* __restrict__ bnA,
    const float* __restrict__ bnB, float* __restrict__ out, GemmPR p) {
  extern __shared__ char smem[];
  const int z = blockIdx.z;
  const int NKT = p.K[z] >> 6;
  const char* Ag = (const char*)(grouped + p.goff[z]) +
                   (size_t)blockIdx.y * NKT * 32768;
  const char* Bg = (const char*)(wbf + p.woff[z]) +
                   (size_t)blockIdx.x * NKT * 32768;
  const int tid = threadIdx.x;
  const int lane = tid & 63, wid = tid >> 6;
  const int wr = wid >> 2, wc = wid & 3;

  f32x4 acc[8][4];
#pragma unroll
  for (int m = 0; m < 8; ++m)
#pragma unroll
    for (int n = 0; n < 4; ++n) acc[m][n] = (f32x4){0.f, 0.f, 0.f, 0.f};

  for (int kt = 0; kt < NKT; ++kt) {
    const char* srcA = Ag + (size_t)kt * 32768;
    const char* srcB = Bg + (size_t)kt * 32768;
#pragma unroll
    for (int it = 0; it < 4; ++it)
      GLOAD_LDS16(srcA + (it * 512 + tid) * 16, smem + (it * 512 + wid * 64) * 16);
#pragma unroll
    for (int it = 0; it < 4; ++it)
      GLOAD_LDS16(srcB + (it * 512 + tid) * 16,
                  smem + 32768 + (it * 512 + wid * 64) * 16);
    asm volatile("s_waitcnt vmcnt(0)" ::: "memory");
    __syncthreads();
#pragma unroll
    for (int ks = 0; ks < 2; ++ks) {
      bf16x8 af[8], bv[4];
#pragma unroll
      for (int m = 0; m < 8; ++m) {
        int row = wr * 128 + m * 16 + (lane & 15);
        int byte = (row * 128 + ks * 64 + ((lane >> 4) * 16)) ^ ((lane & 7) << 4);
        af[m] = *reinterpret_cast<const bf16x8*>(smem + byte);
      }
#pragma unroll
      for (int n = 0; n < 4; ++n) {
        int col = wc * 64 + n * 16 + (lane & 15);
        int byte = (col * 128 + ks * 64 + ((lane >> 4) * 16)) ^ ((lane & 7) << 4);
        bv[n] = *reinterpret_cast<const bf16x8*>(smem + 32768 + byte);
      }
#pragma unroll
      for (int m = 0; m < 8; ++m)
#pragma unroll
        for (int n = 0; n < 4; ++n)
          acc[m][n] = __builtin_amdgcn_mfma_f32_16x16x32_bf16(af[m], bv[n],
                                                              acc[m][n], 0, 0, 0);
    }
    __syncthreads();
  }

  const float* bA = bnA + p.bnoff[z];
  const float* bB = bnB + p.bnoff[z];
  float* O = out + (size_t)p.outoff[z];
#pragma unroll
  for (int n = 0; n < 4; ++n) {
    int o = blockIdx.x * 256 + wc * 64 + n * 16 + (lane & 15);
    float sA = bA[o], sB = bB[o];
#pragma unroll
    for (int m = 0; m < 8; ++m) {
      float v = fmaxf(fmaxf(acc[m][n][0], acc[m][n][1]),
                      fmaxf(acc[m][n][2], acc[m][n][3]));
      v = fmaxf(v, __shfl_xor(v, 16));
      v = fmaxf(v, __shfl_xor(v, 32));
      if (lane < 16) {
        int group = blockIdx.y * 16 + wr * 8 + m;
        float val = fmaf(v, sA, sB);
        O[(size_t)group * 1024 + o] = fmaxf(val, 0.f);
      }
    }
  }
}

// ---------------------------------------------------------------- host
extern "C" void kernel_launch(void* const* d_in, const int* in_sizes, int n_in,
                              void* d_out, int out_size, void* d_ws,
                              size_t ws_size, hipStream_t stream) {
  (void)in_sizes; (void)n_in; (void)out_size; (void)ws_size;
  const float *fs[4], *xs[4], *ft[4], *xt[4];
  for (int i = 0; i < 4; ++i) {
    fs[i] = (const float*)d_in[4 * i + 0];
    xs[i] = (const float*)d_in[4 * i + 1];
    ft[i] = (const float*)d_in[4 * i + 2];
    xt[i] = (const float*)d_in[4 * i + 3];
  }
  const float* Ws = (const float*)d_in[16];
  const float* bWs = (const float*)d_in[17];
  const float* gs = (const float*)d_in[18];
  const float* bes = (const float*)d_in[19];
  const float* mus = (const float*)d_in[20];
  const float* vs = (const float*)d_in[21];
  const float* Wt0 = (const float*)d_in[22];
  const float* Wt123 = (const float*)d_in[23];
  const float* bWt = (const float*)d_in[24];
  const float* gt = (const float*)d_in[25];
  const float* bet = (const float*)d_in[26];
  const float* mut = (const float*)d_in[27];
  const float* vt = (const float*)d_in[28];

  char* ws = (char*)d_ws;
  float* newxyz = (float*)(ws + 0);
  int* idxbuf = (int*)(ws + 16384);
  float* bnA = (float*)(ws + 409600);
  float* bnB = (float*)(ws + 442368);
  char* wbf = ws + 475136;
  char* grouped = ws + 6242304;

  static const int NSarr[4] = {2048, 1024, 512, 256};
  const unsigned goff[8] = {0u,        4194304u,  8388608u,  12582912u,
                            16777216u, 33554432u, 37748736u, 41943040u};
  const unsigned woff[8] = {0u,       262144u,  524288u,  786432u,
                            1048576u, 2097152u, 2359296u, 2621440u};

  prep_kernel<<<11296, 256, 0, stream>>>(Ws, Wt0, Wt123, bWs, gs, bes, mus, vs,
                                         bWt, gt, bet, mut, vt, wbf, bnA, bnB);
  fps_kernel<<<16, 64, 0, stream>>>(xt[3], newxyz);

  KnnP kp;
  for (int i = 0; i < 4; ++i) {
    kp.xyz[i] = xs[i];
    kp.xyz[4 + i] = xt[i];
  }
  knn_kernel<<<2048, 256, 0, stream>>>(kp, newxyz, idxbuf);

  GatherP gp;
  unsigned cum = 0;
  for (int c = 0; c < 8; ++c) {
    int scale = c & 3;
    int K = (c == 4) ? 1024 : 256;
    gp.feat[c] = (c < 4) ? fs[scale] : ft[scale];
    gp.n[c] = NSarr[scale];
    gp.base16[c] = cum;
    gp.goffB[c] = goff[c] * 2u;
    gp.lsh[c] = (K == 1024) ? 7 : 5;
    gp.NKT[c] = K >> 6;
    cum += 16384u * (unsigned)(K / 8);
  }
  gp.base16[8] = cum;
  gather_kernel<<<(cum + 255u) / 256u, 256, 0, stream>>>(gp, idxbuf, grouped);

  // zi order: light combos first, heavy (c=4, K=1024) last
  static const int co[8] = {0, 1, 2, 3, 5, 6, 7, 4};
  GemmPR mp;
  for (int zi = 0; zi < 8; ++zi) {
    int c = co[zi];
    mp.goff[zi] = goff[c]; mp.woff[zi] = woff[c];
    mp.outoff[zi] = (unsigned)c * 1048576u;
    mp.bnoff[zi] = (unsigned)c * 1024u;
    mp.K[zi] = (c == 4) ? 1024 : 256;
  }
  hipError_t attr_ok = hipFuncSetAttribute(
      (const void*)gemm_pers_kernel,
      hipFuncAttributeMaxDynamicSharedMemorySize, 131072);
  if (attr_ok == hipSuccess) {
    gemm_pers_kernel<<<256, 512, 131072, stream>>>(
        (const unsigned short*)grouped, (const unsigned short*)wbf, bnA, bnB,
        (float*)d_out, mp);
  } else {
    gemm256_fb_kernel<<<dim3(4, 64, 8), 512, 65536, stream>>>(
        (const unsigned short*)grouped, (const unsigned short*)wbf, bnA, bnB,
        (float*)d_out, mp);
  }
}